// Round 1
// baseline (268.300 us; speedup 1.0000x reference)
//
#include <hip/hip_runtime.h>
#include <hip/hip_bf16.h>

#define FEAT   1024
#define HID    256
#define TSTEPS 24
#define NCLS   10

typedef unsigned int u32;

// ---- workspace layout (float offsets) ----
constexpr int OFF_W1T  = 0;                    // [1024][256] fp32, f-major
constexpr int OFF_W2T  = OFF_W1T + FEAT*HID;   // [256][256]  fp32, f-major
constexpr int OFF_W3T  = OFF_W2T + HID*HID;    // [256][256]  fp32, f-major
constexpr int OFF_WLIT = OFF_W3T + HID*HID;    // [256][10]   fp32, f-major
constexpr int OFF_B1   = OFF_WLIT + HID*NCLS;
constexpr int OFF_B2   = OFF_B1 + HID;
constexpr int OFF_B3   = OFF_B2 + HID;
constexpr int OFF_FLAG = OFF_B3 + HID;         // u32: 1 = inputs are bf16, 0 = fp32

// ---- dtype detector: fp32 data read as bf16 yields mantissa-bytes-as-exponent
// garbage (|v| ~ 1e30 / inf / nan) at even indices; true bf16 N(0,1) stays small.
__global__ void detect_dtype_k(const void* __restrict__ x, u32* __restrict__ flag) {
    __shared__ int bad;
    if (threadIdx.x == 0) bad = 0;
    __syncthreads();
    float v = __bfloat162float(((const __hip_bfloat16*)x)[threadIdx.x]);
    if (!(fabsf(v) < 100.0f)) atomicOr(&bad, 1);   // NaN also fails the < test
    __syncthreads();
    if (threadIdx.x == 0) *flag = bad ? 0u : 1u;
}

__device__ __forceinline__ float rd_any(const void* p, int idx, u32 isbf) {
    return isbf ? __bfloat162float(((const __hip_bfloat16*)p)[idx])
                : ((const float*)p)[idx];
}

// ---- transpose + upconvert all weights into ws (ws re-poisoned every call) ----
__global__ void prep_weights_k(const void* W1, const void* W2, const void* W3,
                               const void* Wli, const void* b1, const void* b2,
                               const void* b3, float* __restrict__ ws) {
    const u32 isbf = ((const u32*)(ws + OFF_FLAG))[0];
    int id = blockIdx.x * 256 + threadIdx.x;
    if (id < FEAT*HID) {                 // W1 [256][1024] -> W1T [1024][256]
        int f = id >> 8, h = id & 255;
        ws[OFF_W1T + id] = rd_any(W1, h*FEAT + f, isbf);
        return;
    }
    id -= FEAT*HID;
    if (id < HID*HID) {                  // W2 -> W2T
        int f = id >> 8, h = id & 255;
        ws[OFF_W2T + id] = rd_any(W2, h*HID + f, isbf);
        return;
    }
    id -= HID*HID;
    if (id < HID*HID) {                  // W3 -> W3T
        int f = id >> 8, h = id & 255;
        ws[OFF_W3T + id] = rd_any(W3, h*HID + f, isbf);
        return;
    }
    id -= HID*HID;
    if (id < HID*NCLS) {                 // Wli [10][256] -> WliT [256][10]
        int f = id / NCLS, c = id - f*NCLS;
        ws[OFF_WLIT + id] = rd_any(Wli, c*HID + f, isbf);
        return;
    }
    id -= HID*NCLS;
    if (id < HID) { ws[OFF_B1 + id] = rd_any(b1, id, isbf); return; }
    id -= HID;
    if (id < HID) { ws[OFF_B2 + id] = rd_any(b2, id, isbf); return; }
    id -= HID;
    if (id < HID) { ws[OFF_B3 + id] = rd_any(b3, id, isbf); return; }
}

// exclusive offset for ordered list compaction: wave shfl-scan + cross-wave LDS.
// Contains one __syncthreads() — doubles as the consume->build separator.
__device__ __forceinline__ uint2 scan_offset(u32 cnt, u32 lane, u32 wv, u32* wsum) {
    u32 x = cnt;
    #pragma unroll
    for (int d = 1; d < 64; d <<= 1) {
        u32 y = __shfl_up(x, d, 64);
        if (lane >= (u32)d) x += y;
    }
    if (lane == 63) wsum[wv] = x;
    __syncthreads();
    u32 base = 0, tot = 0;
    #pragma unroll
    for (int w = 0; w < 4; w++) {
        u32 c = wsum[w];
        tot += c;
        if ((u32)w < wv) base += c;
    }
    return make_uint2(base + x - cnt, tot);
}

// one workgroup per batch row; thread h owns hidden neuron h for all 3 layers;
// states live in registers for all 24 timesteps. Spike lists in LDS.
__global__ __launch_bounds__(256) void snn_main_k(const void* __restrict__ xin,
                                                  const float* __restrict__ ws,
                                                  void* __restrict__ out) {
    const u32 isbf = ((const u32*)(ws + OFF_FLAG))[0];
    const int row  = blockIdx.x;
    const u32 tid  = threadIdx.x;
    const u32 lane = tid & 63;
    const u32 wv   = tid >> 6;

    const float* W1T = ws + OFF_W1T;
    const float* W2T = ws + OFF_W2T;
    const float* W3T = ws + OFF_W3T;
    const float* WLT = ws + OFF_WLIT;

    __shared__ u32 list[FEAT];
    __shared__ u32 wsum[4];
    __shared__ float vo_s[NCLS], io_s[NCLS];

    // encoder features tid*4 .. tid*4+3 (contiguous per thread -> ascending-f lists)
    float xr[4], venc[4];
    if (isbf) {
        const __hip_bfloat16* xp = (const __hip_bfloat16*)xin + (size_t)row*FEAT + tid*4;
        #pragma unroll
        for (int k = 0; k < 4; k++) xr[k] = __bfloat162float(xp[k]);
    } else {
        const float* xp = (const float*)xin + (size_t)row*FEAT + tid*4;
        #pragma unroll
        for (int k = 0; k < 4; k++) xr[k] = xp[k];
    }
    #pragma unroll
    for (int k = 0; k < 4; k++) venc[k] = 0.0f;

    float v1 = 0.f, i1 = 0.f, v2 = 0.f, i2 = 0.f, v3 = 0.f, i3 = 0.f;
    const float b1v = ws[OFF_B1 + tid];
    const float b2v = ws[OFF_B2 + tid];
    const float b3v = ws[OFF_B3 + tid];
    if (tid < NCLS) { vo_s[tid] = 0.f; io_s[tid] = 0.f; }
    __syncthreads();

    for (int t = 0; t < TSTEPS; t++) {
        // ---- encoder: v += 0.1*(x - v); z = v > 1.0; reset ----
        u32 m4 = 0;
        #pragma unroll
        for (int k = 0; k < 4; k++) {
            float v = venc[k];
            v = v + 0.1f * (xr[k] - v);
            bool z = v > 1.0f;
            venc[k] = z ? 0.0f : v;
            m4 |= (z ? 1u : 0u) << k;
        }
        uint2 sE = scan_offset(__popc(m4), lane, wv, wsum);
        u32 pos = sE.x;
        #pragma unroll
        for (int k = 0; k < 4; k++)
            if (m4 & (1u << k)) list[pos++] = tid*4 + k;
        const u32 nE = sE.y;
        __syncthreads();

        // ---- layer 1: gather active W1 columns (z binary -> exact adds) ----
        float acc = b1v;
        for (u32 j = 0; j < nE; j++) acc += W1T[(size_t)list[j]*HID + tid];
        float o1;
        {
            float vd = v1 + 0.1f * (i1 - v1);
            i1 = i1 * 0.8f;
            bool z = vd > 0.23f;
            v1 = z ? 0.0f : vd;
            i1 = i1 + acc;
            o1 = z ? 1.0f : 0.0f;
        }

        // ---- layer 2 ----
        uint2 s1 = scan_offset(o1 > 0.f ? 1u : 0u, lane, wv, wsum);
        if (o1 > 0.f) list[s1.x] = tid;
        const u32 n1 = s1.y;
        __syncthreads();

        float acc2 = b2v;
        for (u32 j = 0; j < n1; j++) acc2 += W2T[(size_t)list[j]*HID + tid];
        float o2;
        {
            float vd = v2 + 0.1f * (i2 - v2);
            i2 = i2 * 0.8f;
            bool z = vd > 0.23f;
            v2 = z ? 0.0f : vd;
            i2 = i2 + acc2;
            o2 = (z ? 1.0f : 0.0f) + o1;       // residual: {0,1,2}
        }

        // ---- layer 3 (inputs carry multiplicity 1..2) ----
        uint2 s2 = scan_offset(o2 > 0.f ? 1u : 0u, lane, wv, wsum);
        if (o2 > 0.f) list[s2.x] = tid | ((u32)o2 << 16);
        const u32 n2 = s2.y;
        __syncthreads();

        float acc3 = b3v;
        for (u32 j = 0; j < n2; j++) {
            u32 p = list[j];
            acc3 = fmaf((float)(p >> 16), W3T[(size_t)(p & 0xffffu)*HID + tid], acc3);
        }
        float o3;
        {
            float vd = v3 + 0.1f * (i3 - v3);
            i3 = i3 * 0.8f;
            bool z = vd > 0.23f;
            v3 = z ? 0.0f : vd;
            i3 = i3 + acc3;
            o3 = (z ? 1.0f : 0.0f) + o2;       // residual: {0,1,2,3}
        }

        // ---- LI readout (o3 multiplicity 1..3) ----
        uint2 s3 = scan_offset(o3 > 0.f ? 1u : 0u, lane, wv, wsum);
        if (o3 > 0.f) list[s3.x] = tid | ((u32)o3 << 16);
        const u32 n3 = s3.y;
        __syncthreads();

        if (tid < NCLS) {
            float voc = vo_s[tid], ioc = io_s[tid];
            voc = voc + 0.1f * (ioc - voc);    // vo from OLD io
            float a = 0.f;
            for (u32 j = 0; j < n3; j++) {
                u32 p = list[j];
                a = fmaf((float)(p >> 16), WLT[(size_t)(p & 0xffffu)*NCLS + tid], a);
            }
            io_s[tid] = ioc * 0.8f + a;
            vo_s[tid] = voc;
        }
        // no extra barrier needed: next iteration's scan_offset barrier separates
        // these list/vo reads from the next list build.
    }
    __syncthreads();

    if (tid < NCLS) {
        float v = vo_s[tid];
        if (isbf) ((__hip_bfloat16*)out)[(size_t)row*NCLS + tid] = __float2bfloat16(v);
        else      ((float*)out)[(size_t)row*NCLS + tid] = v;
    }
}

extern "C" void kernel_launch(void* const* d_in, const int* in_sizes, int n_in,
                              void* d_out, int out_size, void* d_ws, size_t ws_size,
                              hipStream_t stream) {
    const void* x   = d_in[0];
    const void* W1  = d_in[1];
    const void* b1  = d_in[2];
    const void* W2  = d_in[3];
    const void* b2  = d_in[4];
    const void* W3  = d_in[5];
    const void* b3  = d_in[6];
    const void* Wli = d_in[7];
    float* ws = (float*)d_ws;
    const int batch = in_sizes[0] / FEAT;   // 4096

    u32* flag = (u32*)(ws + OFF_FLAG);
    detect_dtype_k<<<1, 256, 0, stream>>>(x, flag);

    const int prep_elems = FEAT*HID + HID*HID + HID*HID + HID*NCLS + 3*HID;
    prep_weights_k<<<(prep_elems + 255)/256, 256, 0, stream>>>(W1, W2, W3, Wli, b1, b2, b3, ws);

    snn_main_k<<<batch, 256, 0, stream>>>(x, ws, d_out);
}

// Round 2
// 166.625 us; speedup vs baseline: 1.6102x; 1.6102x over previous
//
#include <hip/hip_runtime.h>
#include <hip/hip_bf16.h>

#define FEAT   1024
#define HID    256
#define TSTEPS 24
#define NCLS   10

typedef unsigned int u32;
typedef unsigned long long u64;

// ---- workspace layout (float offsets) ----
constexpr int OFF_W1T  = 0;                    // [1024][256] fp32, f-major (W1 transposed)
constexpr int OFF_W2T  = OFF_W1T + FEAT*HID;   // [256][256]  fp32, f-major
constexpr int OFF_W3T  = OFF_W2T + HID*HID;    // [256][256]  fp32, f-major
constexpr int OFF_WLI  = OFF_W3T + HID*HID;    // [10][256]   fp32, plain copy (NOT transposed)
constexpr int OFF_B1   = OFF_WLI + NCLS*HID;
constexpr int OFF_B2   = OFF_B1 + HID;
constexpr int OFF_B3   = OFF_B2 + HID;
constexpr int OFF_FLAG = OFF_B3 + HID;         // u32: 1 = inputs are bf16, 0 = fp32

// ---- LI readout is linear: vo_24 = sum_t coef[t] * (o3_t @ Wli^T).
// coef backward recurrence: c_23 = 0; c_{u-1} = 0.8*c_u + 0.1*0.9^(23-u).
struct CoefT { float c[TSTEPS]; };
constexpr CoefT make_coef() {
    CoefT r{};
    double c = 0.0;          // c_23
    double p9 = 1.0;         // 0.9^(23-u) for u=23
    r.c[TSTEPS-1] = 0.0f;
    for (int u = TSTEPS-1; u > 0; u--) {
        c = 0.8 * c + 0.1 * p9;
        p9 *= 0.9;
        r.c[u-1] = (float)c;
    }
    return r;
}
__device__ constexpr CoefT COEF = make_coef();

// ---- dtype detector: fp32 data read as bf16 yields exponent-garbage (~1e30/inf/nan).
__global__ void detect_dtype_k(const void* __restrict__ x, u32* __restrict__ flag) {
    __shared__ int bad;
    if (threadIdx.x == 0) bad = 0;
    __syncthreads();
    float v = __bfloat162float(((const __hip_bfloat16*)x)[threadIdx.x]);
    if (!(fabsf(v) < 100.0f)) atomicOr(&bad, 1);
    __syncthreads();
    if (threadIdx.x == 0) *flag = bad ? 0u : 1u;
}

__device__ __forceinline__ float rd_any(const void* p, int idx, u32 isbf) {
    return isbf ? __bfloat162float(((const __hip_bfloat16*)p)[idx])
                : ((const float*)p)[idx];
}

// ---- transpose/upconvert weights into ws ----
__global__ void prep_weights_k(const void* W1, const void* W2, const void* W3,
                               const void* Wli, const void* b1, const void* b2,
                               const void* b3, float* __restrict__ ws) {
    const u32 isbf = ((const u32*)(ws + OFF_FLAG))[0];
    int id = blockIdx.x * 256 + threadIdx.x;
    if (id < FEAT*HID) {                 // W1 [256][1024] -> W1T [1024][256]
        int f = id >> 8, h = id & 255;
        ws[OFF_W1T + id] = rd_any(W1, h*FEAT + f, isbf);
        return;
    }
    id -= FEAT*HID;
    if (id < HID*HID) {                  // W2 -> W2T
        int f = id >> 8, h = id & 255;
        ws[OFF_W2T + id] = rd_any(W2, h*HID + f, isbf);
        return;
    }
    id -= HID*HID;
    if (id < HID*HID) {                  // W3 -> W3T
        int f = id >> 8, h = id & 255;
        ws[OFF_W3T + id] = rd_any(W3, h*HID + f, isbf);
        return;
    }
    id -= HID*HID;
    if (id < NCLS*HID) {                 // Wli [10][256] plain fp32 copy
        ws[OFF_WLI + id] = rd_any(Wli, id, isbf);
        return;
    }
    id -= NCLS*HID;
    if (id < HID) { ws[OFF_B1 + id] = rd_any(b1, id, isbf); return; }
    id -= HID;
    if (id < HID) { ws[OFF_B2 + id] = rd_any(b2, id, isbf); return; }
    id -= HID;
    if (id < HID) { ws[OFF_B3 + id] = rd_any(b3, id, isbf); return; }
}

__device__ __forceinline__ float bits_as_f32(u32 b) { return __uint_as_float(b); }

// gather one weight column (uniform col) as float4 into acc
__device__ __forceinline__ void add_col(float* acc, const float* __restrict__ Wt,
                                        u32 col, u32 lane4) {
    col = (u32)__builtin_amdgcn_readfirstlane((int)col);  // pin uniform -> saddr form
    const float4 w = *(const float4*)(Wt + ((size_t)col << 8) + lane4);
    acc[0] += w.x; acc[1] += w.y; acc[2] += w.z; acc[3] += w.w;
}

// One wave per batch row. Lane owns hidden neurons 4*lane..4*lane+3 and
// encoder features f = k*64 + lane (k=0..15). Spike sets = ballot masks in
// SGPRs; gathers are scalar ctz-chains over uniform masks. No LDS, no barriers.
template<int ISBF>
__global__ __launch_bounds__(256) void snn_k(const void* __restrict__ xin,
                                             const float* __restrict__ ws,
                                             void* __restrict__ out) {
    const u32 flag = ((const u32*)(ws + OFF_FLAG))[0];
    if (flag != (u32)ISBF) return;

    const u32 tid  = threadIdx.x;
    const u32 lane = tid & 63;
    const u32 wv   = tid >> 6;
    const int row  = blockIdx.x * 4 + wv;
    const u32 lane4 = lane * 4;

    const float* __restrict__ W1T = ws + OFF_W1T;
    const float* __restrict__ W2T = ws + OFF_W2T;
    const float* __restrict__ W3T = ws + OFF_W3T;
    const float* __restrict__ WLI = ws + OFF_WLI;

    // ---- load x (16 features per lane) ----
    u32   xpk[8];    // bf16 path: packed pairs (features 2j, 2j+1)
    float xf[16];    // fp32 path
    if constexpr (ISBF) {
        const unsigned short* xp = (const unsigned short*)xin + (size_t)row*FEAT;
        #pragma unroll
        for (int j = 0; j < 8; j++) {
            u32 lo = xp[(2*j)*64 + lane];
            u32 hi = xp[(2*j+1)*64 + lane];
            xpk[j] = lo | (hi << 16);
        }
    } else {
        const float* xp = (const float*)xin + (size_t)row*FEAT;
        #pragma unroll
        for (int k = 0; k < 16; k++) xf[k] = xp[k*64 + lane];
    }

    float venc[16];
    #pragma unroll
    for (int k = 0; k < 16; k++) venc[k] = 0.0f;

    float v1[4], i1[4], v2[4], i2[4], v3[4], i3[4], g[4];
    #pragma unroll
    for (int k = 0; k < 4; k++) {
        v1[k]=0.f; i1[k]=0.f; v2[k]=0.f; i2[k]=0.f; v3[k]=0.f; i3[k]=0.f; g[k]=0.f;
    }
    const float4 b1v = *(const float4*)(ws + OFF_B1 + lane4);
    const float4 b2v = *(const float4*)(ws + OFF_B2 + lane4);
    const float4 b3v = *(const float4*)(ws + OFF_B3 + lane4);

    for (int t = 0; t < TSTEPS; t++) {
        // ---- encoder + fused layer-1 gather ----
        float a1[4] = {b1v.x, b1v.y, b1v.z, b1v.w};
        #pragma unroll
        for (int k = 0; k < 16; k++) {
            float xk;
            if constexpr (ISBF)
                xk = (k & 1) ? bits_as_f32(xpk[k>>1] & 0xffff0000u)
                             : bits_as_f32(xpk[k>>1] << 16);
            else
                xk = xf[k];
            float vd = venc[k] + 0.1f * (xk - venc[k]);
            bool z = vd > 1.0f;
            venc[k] = z ? 0.0f : vd;
            u64 m = __ballot(z);
            while (m) {
                u32 p = (u32)__builtin_ctzll(m);
                m &= m - 1;
                add_col(a1, W1T, (u32)(k << 6) | p, lane4);
            }
        }

        // ---- layer 1 LIF ----
        float o1v[4]; u64 m1[4];
        #pragma unroll
        for (int kk = 0; kk < 4; kk++) {
            float vd = v1[kk] + 0.1f * (i1[kk] - v1[kk]);
            i1[kk] = i1[kk] * 0.8f;
            bool z = vd > 0.23f;
            v1[kk] = z ? 0.0f : vd;
            i1[kk] = i1[kk] + a1[kk];
            o1v[kk] = z ? 1.0f : 0.0f;
            m1[kk] = __ballot(z);
        }

        // ---- layer 2 gather (z1 cols; neuron f = 4p+kk) ----
        float a2[4] = {b2v.x, b2v.y, b2v.z, b2v.w};
        #pragma unroll
        for (int kk = 0; kk < 4; kk++) {
            u64 m = m1[kk];
            while (m) {
                u32 p = (u32)__builtin_ctzll(m);
                m &= m - 1;
                add_col(a2, W2T, (p << 2) | (u32)kk, lane4);
            }
        }

        // ---- layer 2 LIF, o2 = z2 + o1 ----
        float o2v[4]; u64 m2[4];
        #pragma unroll
        for (int kk = 0; kk < 4; kk++) {
            float vd = v2[kk] + 0.1f * (i2[kk] - v2[kk]);
            i2[kk] = i2[kk] * 0.8f;
            bool z = vd > 0.23f;
            v2[kk] = z ? 0.0f : vd;
            i2[kk] = i2[kk] + a2[kk];
            o2v[kk] = (z ? 1.0f : 0.0f) + o1v[kk];
            m2[kk] = __ballot(z);
        }

        // ---- layer 3 gather: o2@W3 = z2@W3 + z1@W3 (binary masks) ----
        float a3[4] = {b3v.x, b3v.y, b3v.z, b3v.w};
        #pragma unroll
        for (int kk = 0; kk < 4; kk++) {
            u64 m = m2[kk];
            while (m) {
                u32 p = (u32)__builtin_ctzll(m);
                m &= m - 1;
                add_col(a3, W3T, (p << 2) | (u32)kk, lane4);
            }
        }
        #pragma unroll
        for (int kk = 0; kk < 4; kk++) {
            u64 m = m1[kk];
            while (m) {
                u32 p = (u32)__builtin_ctzll(m);
                m &= m - 1;
                add_col(a3, W3T, (p << 2) | (u32)kk, lane4);
            }
        }

        // ---- layer 3 LIF, o3 = z3 + o2; linear-readout accumulation ----
        const float cf = COEF.c[t];
        #pragma unroll
        for (int kk = 0; kk < 4; kk++) {
            float vd = v3[kk] + 0.1f * (i3[kk] - v3[kk]);
            i3[kk] = i3[kk] * 0.8f;
            bool z = vd > 0.23f;
            v3[kk] = z ? 0.0f : vd;
            i3[kk] = i3[kk] + a3[kk];
            float o3 = (z ? 1.0f : 0.0f) + o2v[kk];
            g[kk] += cf * o3;
        }
    }

    // ---- epilogue: vo_24[c] = sum_h g[h]*Wli[c][h], reduce across wave ----
    float s[NCLS];
    #pragma unroll
    for (int c = 0; c < NCLS; c++) {
        const float4 w = *(const float4*)(WLI + c*HID + lane4);
        float p = g[0]*w.x + g[1]*w.y + g[2]*w.z + g[3]*w.w;
        #pragma unroll
        for (int d = 32; d > 0; d >>= 1) p += __shfl_xor(p, d, 64);
        s[c] = p;
    }
    if (lane == 0) {
        if constexpr (ISBF) {
            __hip_bfloat16* o = (__hip_bfloat16*)out + (size_t)row*NCLS;
            #pragma unroll
            for (int c = 0; c < NCLS; c++) o[c] = __float2bfloat16(s[c]);
        } else {
            float* o = (float*)out + (size_t)row*NCLS;
            #pragma unroll
            for (int c = 0; c < NCLS; c++) o[c] = s[c];
        }
    }
}

extern "C" void kernel_launch(void* const* d_in, const int* in_sizes, int n_in,
                              void* d_out, int out_size, void* d_ws, size_t ws_size,
                              hipStream_t stream) {
    const void* x   = d_in[0];
    const void* W1  = d_in[1];
    const void* b1  = d_in[2];
    const void* W2  = d_in[3];
    const void* b2  = d_in[4];
    const void* W3  = d_in[5];
    const void* b3  = d_in[6];
    const void* Wli = d_in[7];
    float* ws = (float*)d_ws;
    const int batch = in_sizes[0] / FEAT;   // 4096

    u32* flag = (u32*)(ws + OFF_FLAG);
    detect_dtype_k<<<1, 256, 0, stream>>>(x, flag);

    const int prep_elems = FEAT*HID + HID*HID + HID*HID + NCLS*HID + 3*HID;
    prep_weights_k<<<(prep_elems + 255)/256, 256, 0, stream>>>(W1, W2, W3, Wli, b1, b2, b3, ws);

    const int grid = batch / 4;             // 4 rows (waves) per block
    snn_k<1><<<grid, 256, 0, stream>>>(x, ws, d_out);
    snn_k<0><<<grid, 256, 0, stream>>>(x, ws, d_out);
}